// Round 2
// baseline (236.542 us; speedup 1.0000x reference)
//
#include <hip/hip_runtime.h>

// Instant-NGP hash-grid encode, single fused kernel, XCD-pinned temporal
// phases, direct per-level output stores (transpose-free, ws-free).
//
// Round-2 synthesis of two proven results:
// - Round-0/4 schedule (balanced): XCD x runs level 8+x exclusively first
//   (hot set = one 4MB table, fits the private 4MB L2), then a 1/8 slice of
//   level 7 (also a full-table level), then the cheap small levels. Each XCD
//   carries ~1.125 "hard" (full-4MB-table) levels -> balanced. The round-1
//   odd/even split was UNbalanced (5 hard levels on 5 XCDs in pass A, 4 in
//   pass B, easy XCDs idle) and serialized two hard-level waves: 85+87us.
// - Round-1 pb proved direct partial-line nt stores to out from 8 XCDs are
//   correct and cheap (2x HBM write amplification @ 17% util = harmless).
//   So store each level's 8B result straight to out + p*32 + 2*level and
//   delete the transpose kernel (+1 store req/pt-level = +6% gather time,
//   -37us transpose kernel, -1 launch).
//
// Kept from previous rounds (proven):
// - x-paired 16B gathers: corners (x0,..) and (x0+1,..) share an aligned
//   16B line when x0 even -> 4 unconditional 16B + ~2 predicated 8B loads
//   per point-level (6 req avg vs 8). 87% of the 16 req/cyc/XCD L2 ceiling.
// - NO agent-scope/sc0 loads (they bypass the per-XCD L2) [round 7].
// - Pin all gather results live via empty asm, else the compiler sinks
//   loads and MLP collapses [round 6].
// - nt stores for output so the pinned table isn't evicted from L2.

#define HG_N_LEVELS   16
#define HG_TABLE_SIZE 524288u
#define HG_TABLE_MASK (HG_TABLE_SIZE - 1u)

typedef float vf2 __attribute__((ext_vector_type(2)));
typedef float vf4 __attribute__((ext_vector_type(4)));

// Per-point prep: 4 yz-hash partials + weights + x0.
__device__ __forceinline__ void hg_prep2(
    float px, float py, float pz, float res,
    unsigned* __restrict__ s, float* __restrict__ wyz,
    unsigned* __restrict__ x0out, float* __restrict__ wx)
{
    const float lim = 1.0f - 1e-6f;
    float ux = fminf(fmaxf(px + 0.5f, 0.0f), lim);
    float uy = fminf(fmaxf(py + 0.5f, 0.0f), lim);
    float uz = fminf(fmaxf(pz + 0.5f, 0.0f), lim);
    float fx = ux * res, fy = uy * res, fz = uz * res;
    float x0f = floorf(fx), y0f = floorf(fy), z0f = floorf(fz);
    float wx1 = fx - x0f, wy1 = fy - y0f, wz1 = fz - z0f;
    float wx0 = 1.0f - wx1, wy0 = 1.0f - wy1, wz0 = 1.0f - wz1;
    unsigned x0 = (unsigned)x0f, y0 = (unsigned)y0f, z0 = (unsigned)z0f;
    const unsigned P1 = 2654435761u, P2 = 805459861u;
    unsigned hy0 = y0 * P1, hy1 = (y0 + 1u) * P1;
    unsigned hz0 = z0 * P2, hz1 = (z0 + 1u) * P2;
    s[0] = hy0 ^ hz0;  wyz[0] = wy0 * wz0;
    s[1] = hy0 ^ hz1;  wyz[1] = wy0 * wz1;
    s[2] = hy1 ^ hz0;  wyz[2] = wy1 * wz0;
    s[3] = hy1 ^ hz1;  wyz[3] = wy1 * wz1;
    *x0out = x0; wx[0] = wx0; wx[1] = wx1;
}

// Legacy full-prep for tail paths.
__device__ __forceinline__ void hg_prep(
    float px, float py, float pz, float res,
    unsigned* __restrict__ idx, float* __restrict__ w)
{
    unsigned s[4]; float wyz[4], wx[2]; unsigned x0;
    hg_prep2(px, py, pz, res, s, wyz, &x0, wx);
    #pragma unroll
    for (int j = 0; j < 4; ++j) {
        idx[j]     = (x0 ^ s[j]) & HG_TABLE_MASK;        w[j]     = wx[0] * wyz[j];
        idx[4 + j] = ((x0 + 1u) ^ s[j]) & HG_TABLE_MASK; w[4 + j] = wx[1] * wyz[j];
    }
}

// Two-point gather for one level: returns {oax, oay, obx, oby}.
// x-paired 16B loads + predicated 8B odd loads + asm pin (proven structure).
__device__ __forceinline__ vf4 hg_gather2(
    const float2* __restrict__ tbl, float res,
    float ax, float ay, float az, float bx, float by, float bz)
{
    unsigned sA[4], sB[4], x0A, x0B;
    float wyzA[4], wyzB[4], wxA[2], wxB[2];
    hg_prep2(ax, ay, az, res, sA, wyzA, &x0A, wxA);
    hg_prep2(bx, by, bz, res, sB, wyzB, &x0B, wxB);

    unsigned iA0[4], iA1[4], iB0[4], iB1[4];
    #pragma unroll
    for (int j = 0; j < 4; ++j) {
        iA0[j] = (x0A ^ sA[j]) & HG_TABLE_MASK;
        iA1[j] = ((x0A + 1u) ^ sA[j]) & HG_TABLE_MASK;
        iB0[j] = (x0B ^ sB[j]) & HG_TABLE_MASK;
        iB1[j] = ((x0B + 1u) ^ sB[j]) & HG_TABLE_MASK;
    }
    const bool oddA = (x0A & 1u) != 0u;
    const bool oddB = (x0B & 1u) != 0u;

    // 8 unconditional 16B paired loads (line containing corner x-offset 0;
    // for even x0 the same 16B also holds corner x-offset 1).
    vf4 qA[4], qB[4];
    #pragma unroll
    for (int j = 0; j < 4; ++j) qA[j] = *(const vf4*)(tbl + (iA0[j] & ~1u));
    #pragma unroll
    for (int j = 0; j < 4; ++j) qB[j] = *(const vf4*)(tbl + (iB0[j] & ~1u));

    // predicated 8B loads of the +x corner for odd-x0 lanes only
    vf2 eA[4], eB[4];
    #pragma unroll
    for (int j = 0; j < 4; ++j) { eA[j] = (vf2)(0.f); eB[j] = (vf2)(0.f); }
    if (oddA) {
        #pragma unroll
        for (int j = 0; j < 4; ++j) eA[j] = *(const vf2*)(tbl + iA1[j]);
    }
    if (oddB) {
        #pragma unroll
        for (int j = 0; j < 4; ++j) eB[j] = *(const vf2*)(tbl + iB1[j]);
    }

    // Pin everything simultaneously live -> loads can't sink, MLP stays up.
    asm volatile(""
        : "+v"(qA[0]), "+v"(qA[1]), "+v"(qA[2]), "+v"(qA[3]),
          "+v"(qB[0]), "+v"(qB[1]), "+v"(qB[2]), "+v"(qB[3]),
          "+v"(eA[0]), "+v"(eA[1]), "+v"(eA[2]), "+v"(eA[3]),
          "+v"(eB[0]), "+v"(eB[1]), "+v"(eB[2]), "+v"(eB[3])
        :
        : "memory");

    float oax = 0.f, oay = 0.f, obx = 0.f, oby = 0.f;
    #pragma unroll
    for (int j = 0; j < 4; ++j) {
        bool hi = (iA0[j] & 1u) != 0u;
        vf2 lo;  lo.x  = qA[j].x; lo.y  = qA[j].y;
        vf2 hiv; hiv.x = qA[j].z; hiv.y = qA[j].w;
        vf2 f0 = hi ? hiv : lo;                  // corner x-offset 0
        vf2 f1 = oddA ? eA[j] : (hi ? lo : hiv); // corner x-offset 1
        float w0 = wxA[0] * wyzA[j], w1 = wxA[1] * wyzA[j];
        oax += w0 * f0.x + w1 * f1.x;
        oay += w0 * f0.y + w1 * f1.y;
    }
    #pragma unroll
    for (int j = 0; j < 4; ++j) {
        bool hi = (iB0[j] & 1u) != 0u;
        vf2 lo;  lo.x  = qB[j].x; lo.y  = qB[j].y;
        vf2 hiv; hiv.x = qB[j].z; hiv.y = qB[j].w;
        vf2 f0 = hi ? hiv : lo;
        vf2 f1 = oddB ? eB[j] : (hi ? lo : hiv);
        float w0 = wxB[0] * wyzB[j], w1 = wxB[1] * wyzB[j];
        obx += w0 * f0.x + w1 * f1.x;
        oby += w0 * f0.y + w1 * f1.y;
    }

    vf4 r; r.x = oax; r.y = oay; r.z = obx; r.w = oby;
    return r;
}

// Scalar single-point gather (tail path).
__device__ __forceinline__ vf2 hg_gather1(
    const float2* __restrict__ tbl, float res,
    float px, float py, float pz)
{
    unsigned idx[8]; float w[8];
    hg_prep(px, py, pz, res, idx, w);
    vf2 f[8];
    #pragma unroll
    for (int k = 0; k < 8; ++k) f[k] = *(const vf2*)(tbl + idx[k]);
    float sx = 0.f, sy = 0.f;
    #pragma unroll
    for (int k = 0; k < 8; ++k) { sx += w[k] * f[k].x; sy += w[k] * f[k].y; }
    vf2 v; v.x = sx; v.y = sy;
    return v;
}

// ---------- Fused: balanced temporally-phased gather, direct out stores ----------
__global__ __launch_bounds__(256) void hashgrid_fused(
    const float* __restrict__ xyz,
    const float* __restrict__ tables,
    const int*   __restrict__ resolutions,
    float*       __restrict__ out,      // [n][32] floats
    int n_points)
{
    const int x    = blockIdx.x & 7;    // XCD (blockIdx%8 round-robin)
    const int slot = blockIdx.x >> 3;   // position in XCD x's work queue
    const int C    = (n_points + 511) >> 9;  // 512-point chunks per level
    const int C8   = (C + 7) >> 3;

    // Phase 1: level 8+x exclusively (one 4MB table per XCD L2).
    // Phase 2: level 7 (full-table level) split 8 ways.
    // Phase 3: small levels (L2/L1-resident working sets), 0-5 one XCD each,
    //          level 6 (2.2MB) split across two XCDs.
    int level, chunk;
    if (slot < C)            { level = 8 + x; chunk = slot; }
    else if (slot < C + C8)  { int j = slot - C; level = 7; chunk = x + (j << 3); }
    else                     { int j = slot - C - C8;
                               if (x >= 6) { level = 6; chunk = (x - 6) + (j << 1); }
                               else        { level = x; chunk = j; } }
    if (chunk >= C) return;

    const float res = (float)resolutions[level];
    const float2* __restrict__ tbl =
        (const float2*)tables + (size_t)level * HG_TABLE_SIZE;

    const int p0 = (chunk << 9) + ((int)threadIdx.x << 1);   // 2 pts/thread
    if (p0 >= n_points) return;

    float* op = out + (size_t)p0 * 32 + 2 * level;   // 8B-aligned level slot

    if (p0 + 1 < n_points) {
        const float* xp = xyz + (size_t)p0 * 3;
        vf2 c0 = *(const vf2*)(xp);
        vf2 c1 = *(const vf2*)(xp + 2);
        vf2 c2 = *(const vf2*)(xp + 4);
        vf4 g = hg_gather2(tbl, res, c0.x, c0.y, c1.x, c1.y, c2.x, c2.y);
        vf2 a; a.x = g.x; a.y = g.y;
        vf2 b; b.x = g.z; b.y = g.w;
        __builtin_nontemporal_store(a, (vf2*)op);
        __builtin_nontemporal_store(b, (vf2*)(op + 32));
    } else {
        vf2 g = hg_gather1(tbl, res,
                           xyz[(size_t)p0 * 3 + 0],
                           xyz[(size_t)p0 * 3 + 1],
                           xyz[(size_t)p0 * 3 + 2]);
        __builtin_nontemporal_store(g, (vf2*)op);
    }
}

extern "C" void kernel_launch(void* const* d_in, const int* in_sizes, int n_in,
                              void* d_out, int out_size, void* d_ws, size_t ws_size,
                              hipStream_t stream) {
    const float* xyz         = (const float*)d_in[0];
    const float* tables      = (const float*)d_in[1];
    const int*   resolutions = (const int*)d_in[2];
    float*       out         = (float*)d_out;

    int n_points = in_sizes[0] / 3;
    int C  = (n_points + 511) >> 9;
    int C8 = (C + 7) >> 3;
    int slots = 2 * C + C8;              // covers the longest XCD queue
    hashgrid_fused<<<8 * slots, 256, 0, stream>>>(
        xyz, tables, resolutions, out, n_points);
}

// Round 3
// 219.878 us; speedup vs baseline: 1.0758x; 1.0758x over previous
//
#include <hip/hip_runtime.h>

// Instant-NGP hash-grid encode. Round-3: revert to the proven round-0
// two-phase structure (balanced XCD-pinned gather -> level-major ws with
// clean 16B+ stores, then a small LDS transpose), with a 4-points-per-thread
// gather to cut the xyz request share.
//
// Cost model (validated rounds 0-2, per-XCD L2 request ceiling 16 req/cyc
// = 38.4 G/s, ~87% achievable):
// - R0 gather: 8 req/pt-level (6 table + 1.5 xyz + 0.5 ws store) balanced
//   across XCDs = 4.2 M req/XCD -> 125 us. Transpose ~16 us (4.2 M req
//   total). Fixed harness overhead ~79 us (R2: single 157 us kernel,
//   236.5 total).
// - R1 lesson: odd/even level split is load-UNbalanced (hard levels 7-15
//   have 4MB working sets; easies are L1/L2-cheap) -> two serialized
//   85+87 us waves. Schedule must give each XCD ~1.125 hard levels.
// - R2 lesson: 8B-granular stores to out[point][level] pay a 32B HBM write
//   sector each (WRITE 131 MB = 4x) plus partial-line FETCH. Direct-store
//   fusion is a loss; keep the 16 us transpose.
// - This round: 4 pts/thread -> xyz = 3 vf4 per 4 points (0.75 req/pt-lvl
//   vs 1.5), total 7.25 req/pt-lvl (-9.4%) -> predicted gather ~112 us.
//
// Kept invariants (proven):
// - x-paired 16B gathers (corners x0,x0+1 share an aligned 16B line when
//   x0 even): 4 unconditional vf4 + avg 2 predicated vf2 per pt-level.
// - NO agent-scope/sc0 loads (bypass per-XCD L2).
// - Pin all gather results live via empty asm (else compiler sinks loads,
//   MLP collapses). Pins split 16+16 operands (asm operand limit).
// - nt stores for bulk output (don't evict the pinned table from L2).

#define HG_N_LEVELS   16
#define HG_TABLE_SIZE 524288u
#define HG_TABLE_MASK (HG_TABLE_SIZE - 1u)

typedef float vf2 __attribute__((ext_vector_type(2)));
typedef float vf4 __attribute__((ext_vector_type(4)));

// Per-point prep: 4 yz-hash partials + weights + x0.
__device__ __forceinline__ void hg_prep2(
    float px, float py, float pz, float res,
    unsigned* __restrict__ s, float* __restrict__ wyz,
    unsigned* __restrict__ x0out, float* __restrict__ wx)
{
    const float lim = 1.0f - 1e-6f;
    float ux = fminf(fmaxf(px + 0.5f, 0.0f), lim);
    float uy = fminf(fmaxf(py + 0.5f, 0.0f), lim);
    float uz = fminf(fmaxf(pz + 0.5f, 0.0f), lim);
    float fx = ux * res, fy = uy * res, fz = uz * res;
    float x0f = floorf(fx), y0f = floorf(fy), z0f = floorf(fz);
    float wx1 = fx - x0f, wy1 = fy - y0f, wz1 = fz - z0f;
    float wx0 = 1.0f - wx1, wy0 = 1.0f - wy1, wz0 = 1.0f - wz1;
    unsigned x0 = (unsigned)x0f, y0 = (unsigned)y0f, z0 = (unsigned)z0f;
    const unsigned P1 = 2654435761u, P2 = 805459861u;
    unsigned hy0 = y0 * P1, hy1 = (y0 + 1u) * P1;
    unsigned hz0 = z0 * P2, hz1 = (z0 + 1u) * P2;
    s[0] = hy0 ^ hz0;  wyz[0] = wy0 * wz0;
    s[1] = hy0 ^ hz1;  wyz[1] = wy0 * wz1;
    s[2] = hy1 ^ hz0;  wyz[2] = wy1 * wz0;
    s[3] = hy1 ^ hz1;  wyz[3] = wy1 * wz1;
    *x0out = x0; wx[0] = wx0; wx[1] = wx1;
}

// Legacy full-prep for tail paths.
__device__ __forceinline__ void hg_prep(
    float px, float py, float pz, float res,
    unsigned* __restrict__ idx, float* __restrict__ w)
{
    unsigned s[4]; float wyz[4], wx[2]; unsigned x0;
    hg_prep2(px, py, pz, res, s, wyz, &x0, wx);
    #pragma unroll
    for (int j = 0; j < 4; ++j) {
        idx[j]     = (x0 ^ s[j]) & HG_TABLE_MASK;        w[j]     = wx[0] * wyz[j];
        idx[4 + j] = ((x0 + 1u) ^ s[j]) & HG_TABLE_MASK; w[4 + j] = wx[1] * wyz[j];
    }
}

// Scalar single-point gather (tail path).
__device__ __forceinline__ vf2 hg_gather1(
    const float2* __restrict__ tbl, float res,
    float px, float py, float pz)
{
    unsigned idx[8]; float w[8];
    hg_prep(px, py, pz, res, idx, w);
    vf2 f[8];
    #pragma unroll
    for (int k = 0; k < 8; ++k) f[k] = *(const vf2*)(tbl + idx[k]);
    float sx = 0.f, sy = 0.f;
    #pragma unroll
    for (int k = 0; k < 8; ++k) { sx += w[k] * f[k].x; sy += w[k] * f[k].y; }
    vf2 v; v.x = sx; v.y = sy;
    return v;
}

// Four-point gather for one level. 24 loads issued before any consumption
// (two 16-operand pins), results in r0={p0.x,p0.y,p1.x,p1.y},
// r1={p2.x,p2.y,p3.x,p3.y}.
__device__ __forceinline__ void hg_gather4(
    const float2* __restrict__ tbl, float res,
    vf4 c0, vf4 c1, vf4 c2, vf4* __restrict__ r0, vf4* __restrict__ r1)
{
    float px[4], py[4], pz[4];
    px[0] = c0.x; py[0] = c0.y; pz[0] = c0.z;
    px[1] = c0.w; py[1] = c1.x; pz[1] = c1.y;
    px[2] = c1.z; py[2] = c1.w; pz[2] = c2.x;
    px[3] = c2.y; py[3] = c2.z; pz[3] = c2.w;

    unsigned s[4][4], x0[4];
    float wyz[4][4], wx[4][2];
    #pragma unroll
    for (int t = 0; t < 4; ++t)
        hg_prep2(px[t], py[t], pz[t], res, s[t], wyz[t], &x0[t], wx[t]);

    unsigned i0[4][4], i1[4][4];
    bool odd[4];
    #pragma unroll
    for (int t = 0; t < 4; ++t) {
        odd[t] = (x0[t] & 1u) != 0u;
        #pragma unroll
        for (int j = 0; j < 4; ++j) {
            i0[t][j] = (x0[t] ^ s[t][j]) & HG_TABLE_MASK;
            i1[t][j] = ((x0[t] + 1u) ^ s[t][j]) & HG_TABLE_MASK;
        }
    }

    // 16 unconditional 16B paired loads (line of corner x-offset 0; for
    // even x0 the same 16B also holds corner x-offset 1).
    vf4 q[4][4];
    #pragma unroll
    for (int t = 0; t < 4; ++t)
        #pragma unroll
        for (int j = 0; j < 4; ++j)
            q[t][j] = *(const vf4*)(tbl + (i0[t][j] & ~1u));

    // predicated 8B loads of the +x corner for odd-x0 lanes only
    vf2 e[4][4];
    #pragma unroll
    for (int t = 0; t < 4; ++t)
        #pragma unroll
        for (int j = 0; j < 4; ++j) e[t][j] = (vf2)(0.f);
    #pragma unroll
    for (int t = 0; t < 4; ++t) {
        if (odd[t]) {
            #pragma unroll
            for (int j = 0; j < 4; ++j) e[t][j] = *(const vf2*)(tbl + i1[t][j]);
        }
    }

    // Pin everything simultaneously live (split: 16-operand asm limit).
    asm volatile(""
        : "+v"(q[0][0]), "+v"(q[0][1]), "+v"(q[0][2]), "+v"(q[0][3]),
          "+v"(q[1][0]), "+v"(q[1][1]), "+v"(q[1][2]), "+v"(q[1][3]),
          "+v"(e[0][0]), "+v"(e[0][1]), "+v"(e[0][2]), "+v"(e[0][3]),
          "+v"(e[1][0]), "+v"(e[1][1]), "+v"(e[1][2]), "+v"(e[1][3])
        :
        : "memory");
    asm volatile(""
        : "+v"(q[2][0]), "+v"(q[2][1]), "+v"(q[2][2]), "+v"(q[2][3]),
          "+v"(q[3][0]), "+v"(q[3][1]), "+v"(q[3][2]), "+v"(q[3][3]),
          "+v"(e[2][0]), "+v"(e[2][1]), "+v"(e[2][2]), "+v"(e[2][3]),
          "+v"(e[3][0]), "+v"(e[3][1]), "+v"(e[3][2]), "+v"(e[3][3])
        :
        : "memory");

    float ox[4], oy[4];
    #pragma unroll
    for (int t = 0; t < 4; ++t) {
        float ax = 0.f, ay = 0.f;
        #pragma unroll
        for (int j = 0; j < 4; ++j) {
            bool hi = (i0[t][j] & 1u) != 0u;
            vf2 lo;  lo.x  = q[t][j].x; lo.y  = q[t][j].y;
            vf2 hiv; hiv.x = q[t][j].z; hiv.y = q[t][j].w;
            vf2 f0 = hi ? hiv : lo;                     // corner x-offset 0
            vf2 f1 = odd[t] ? e[t][j] : (hi ? lo : hiv); // corner x-offset 1
            float w0 = wx[t][0] * wyz[t][j], w1 = wx[t][1] * wyz[t][j];
            ax += w0 * f0.x + w1 * f1.x;
            ay += w0 * f0.y + w1 * f1.y;
        }
        ox[t] = ax; oy[t] = ay;
    }
    vf4 a; a.x = ox[0]; a.y = oy[0]; a.z = ox[1]; a.w = oy[1];
    vf4 b; b.x = ox[2]; b.y = oy[2]; b.z = ox[3]; b.w = oy[3];
    *r0 = a; *r1 = b;
}

// ---------- Phase 1: temporally-phased level-pinned gather -> ws [16][N] ----------
// 1024-point chunks, 256 threads x 4 points.
__global__ __launch_bounds__(256, 3) void hashgrid_gather_lvl(
    const float* __restrict__ xyz,
    const float* __restrict__ tables,
    const int*   __restrict__ resolutions,
    float*       __restrict__ ws,       // [16][n] float2, as floats
    int n_points)
{
    const int x    = blockIdx.x & 7;    // XCD (blockIdx%8 round-robin)
    const int slot = blockIdx.x >> 3;   // position in XCD x's work queue
    const int C    = (n_points + 1023) >> 10;  // 1024-point chunks per level
    const int C8   = (C + 7) >> 3;

    // Phase 1: level 8+x exclusively (one 4MB table per XCD L2).
    // Phase 2: level 7 (full-table level) split 8 ways.
    // Phase 3: small levels; 0-5 one XCD each, level 6 split across two.
    int level, chunk;
    if (slot < C)            { level = 8 + x; chunk = slot; }
    else if (slot < C + C8)  { int j = slot - C; level = 7; chunk = x + (j << 3); }
    else                     { int j = slot - C - C8;
                               if (x >= 6) { level = 6; chunk = (x - 6) + (j << 1); }
                               else        { level = x; chunk = j; } }
    if (chunk >= C) return;

    const float res = (float)resolutions[level];
    const float2* __restrict__ tbl =
        (const float2*)tables + (size_t)level * HG_TABLE_SIZE;
    float* __restrict__ wlev = ws + (size_t)level * n_points * 2;

    const int p0 = (chunk << 10) + ((int)threadIdx.x << 2);   // 4 pts/thread
    if (p0 >= n_points) return;

    if (p0 + 3 < n_points) {
        const float* xp = xyz + (size_t)p0 * 3;   // 48B-aligned (p0 % 4 == 0)
        vf4 c0 = *(const vf4*)(xp);
        vf4 c1 = *(const vf4*)(xp + 4);
        vf4 c2 = *(const vf4*)(xp + 8);
        vf4 r0, r1;
        hg_gather4(tbl, res, c0, c1, c2, &r0, &r1);
        float* wp = wlev + 2 * (size_t)p0;        // 32B-aligned
        __builtin_nontemporal_store(r0, (vf4*)wp);
        __builtin_nontemporal_store(r1, (vf4*)(wp + 4));
    } else {
        for (int p = p0; p < n_points; ++p) {
            vf2 v = hg_gather1(tbl, res,
                               xyz[(size_t)p * 3 + 0],
                               xyz[(size_t)p * 3 + 1],
                               xyz[(size_t)p * 3 + 2]);
            __builtin_nontemporal_store(v, (vf2*)(wlev + 2 * (size_t)p));
        }
    }
}

// ---------- Phase 2: transpose ws [16][N] -> out [N][16], float4 both sides ----------
#define TP_PTS 256
#define TP_STRIDE (2 * TP_PTS + 4)   // floats per LDS row (pad 4 -> <=2-way conflicts)

__global__ __launch_bounds__(256) void hashgrid_transpose(
    const float* __restrict__ ws,
    float*       __restrict__ out,
    int n_points)
{
    __shared__ float tile[16 * TP_STRIDE];   // ~33 KB, level-major
    const int p0 = blockIdx.x * TP_PTS;
    const int t  = (int)threadIdx.x;
    const int npts = min(TP_PTS, n_points - p0);

    #pragma unroll
    for (int it = 0; it < 8; ++it) {
        int r  = it * 2 + (t >> 7);
        int q  = t & 127;
        int pt = q * 2;
        if (pt < npts) {
            const float* src = ws + (size_t)r * n_points * 2 + (size_t)(p0 + pt) * 2;
            vf4 v;
            if (pt + 1 < npts) v = *(const vf4*)src;
            else { vf2 v2 = *(const vf2*)src; v.x = v2.x; v.y = v2.y; v.z = 0.f; v.w = 0.f; }
            *(vf4*)&tile[r * TP_STRIDE + 4 * q] = v;
        }
    }
    __syncthreads();

    #pragma unroll
    for (int it = 0; it < 8; ++it) {
        int linear = it * 256 + t;
        int pt = linear >> 3;
        int v4 = linear & 7;
        if (pt < npts) {
            vf4 v;
            #pragma unroll
            for (int k = 0; k < 4; ++k) {
                int e = 4 * v4 + k;
                int lev = e >> 1, f = e & 1;
                v[k] = tile[lev * TP_STRIDE + 2 * pt + f];
            }
            __builtin_nontemporal_store(
                v, (vf4*)(out + (size_t)(p0 + pt) * 32 + 4 * v4));
        }
    }
}

// ---------- Fallback: single-kernel version (ws too small) ----------
__global__ __launch_bounds__(256) void hashgrid_fwd(
    const float* __restrict__ xyz,
    const float* __restrict__ tables,
    const int*   __restrict__ resolutions,
    float*       __restrict__ out,
    int n_points)
{
    int tid   = blockIdx.x * blockDim.x + threadIdx.x;
    int point = tid >> 4;
    int level = tid & 15;
    if (point >= n_points) return;

    float px = xyz[point * 3 + 0];
    float py = xyz[point * 3 + 1];
    float pz = xyz[point * 3 + 2];
    float res = (float)resolutions[level];
    const float2* __restrict__ tbl =
        (const float2*)tables + (size_t)level * HG_TABLE_SIZE;

    vf2 v = hg_gather1(tbl, res, px, py, pz);
    *(vf2*)(out + (size_t)point * 32 + 2 * level) = v;
}

extern "C" void kernel_launch(void* const* d_in, const int* in_sizes, int n_in,
                              void* d_out, int out_size, void* d_ws, size_t ws_size,
                              hipStream_t stream) {
    const float* xyz         = (const float*)d_in[0];
    const float* tables      = (const float*)d_in[1];
    const int*   resolutions = (const int*)d_in[2];
    float*       out         = (float*)d_out;

    int n_points = in_sizes[0] / 3;
    size_t ws_needed = (size_t)n_points * HG_N_LEVELS * sizeof(float2);

    if (ws_size >= ws_needed) {
        float* ws = (float*)d_ws;
        int C  = (n_points + 1023) >> 10;
        int C8 = (C + 7) >> 3;
        int slots = 2 * C + C8;          // covers the longest XCD queue
        hashgrid_gather_lvl<<<8 * slots, 256, 0, stream>>>(
            xyz, tables, resolutions, ws, n_points);
        int tblocks = (n_points + TP_PTS - 1) / TP_PTS;
        hashgrid_transpose<<<tblocks, 256, 0, stream>>>(ws, out, n_points);
    } else {
        int n_threads = n_points * HG_N_LEVELS;
        hashgrid_fwd<<<(n_threads + 255) / 256, 256, 0, stream>>>(
            xyz, tables, resolutions, out, n_points);
    }
}

// Round 4
// 205.941 us; speedup vs baseline: 1.1486x; 1.0677x over previous
//
#include <hip/hip_runtime.h>

// Instant-NGP hash-grid encode. Round-4: R0 two-phase structure with a
// perfectly-balanced phase-2 schedule (levels 0-7 stride-8 interleaved
// across all XCDs).
//
// Cost model (validated R0-R3):
// - Binding resource: table-gather request service on the critical-path
//   XCD. R0 vs R3: table requests identical (25.2M) -> identical 125 us,
//   despite different xyz/store counts and different VGPR/occupancy.
//   xyz/store micro-opts and per-thread MLP are NOT levers (R3 falsified).
// - Old phase-2/3 gave each XCD one whole easy level; easy levels have
//   unequal effective cost (L1 absorption: L0~0.35 .. L5~0.9 of a hard
//   level) -> critical XCD ~2.0 effective hard-levels, others ~1.6.
// - New: phase 2 = flat list [L7|L6|...|L0] x C chunks, XCD x takes items
//   g = j*8+x. Every XCD: C phase-1 chunks + C phase-2 chunks with an
//   IDENTICAL level mix -> balanced by construction (~1.74 effective).
//   All XCDs process the same level concurrently (loosely synced from the
//   equal phase-1 cost), so per-XCD L2 holds one table at a time. Cost:
//   easy-table HBM replication x8 (~+30MB FETCH, ~5us) - cheap at 12% HBM.
// - R2 lesson: 8B-granular stores to out pay 32B HBM sectors (4x write
//   amp); keep level-major ws (16B stores) + 16us LDS transpose.
// - R1 lesson: whole-level XCD assignment of unequal-cost levels
//   serializes; balance must be by chunks, not levels.
//
// Kept invariants (proven):
// - x-paired 16B gathers: corners (x0,..),(x0+1,..) share an aligned 16B
//   line when x0 even -> 4 unconditional vf4 + avg 2 predicated vf2 per
//   point-level (6 table req/pt-lvl, the floor for this hash).
// - NO agent-scope/sc0 loads (bypass per-XCD L2).
// - Pin gather results live via empty asm (else compiler sinks loads,
//   MLP collapses, VGPR=20).
// - 2 pts/thread, VGPR 40 (<=64 wave-class: full 8 waves/SIMD cap).
// - nt stores for bulk output (don't evict the pinned table from L2).

#define HG_N_LEVELS   16
#define HG_TABLE_SIZE 524288u
#define HG_TABLE_MASK (HG_TABLE_SIZE - 1u)

typedef float vf2 __attribute__((ext_vector_type(2)));
typedef float vf4 __attribute__((ext_vector_type(4)));

// Per-point prep: 4 yz-hash partials + weights + x0.
__device__ __forceinline__ void hg_prep2(
    float px, float py, float pz, float res,
    unsigned* __restrict__ s, float* __restrict__ wyz,
    unsigned* __restrict__ x0out, float* __restrict__ wx)
{
    const float lim = 1.0f - 1e-6f;
    float ux = fminf(fmaxf(px + 0.5f, 0.0f), lim);
    float uy = fminf(fmaxf(py + 0.5f, 0.0f), lim);
    float uz = fminf(fmaxf(pz + 0.5f, 0.0f), lim);
    float fx = ux * res, fy = uy * res, fz = uz * res;
    float x0f = floorf(fx), y0f = floorf(fy), z0f = floorf(fz);
    float wx1 = fx - x0f, wy1 = fy - y0f, wz1 = fz - z0f;
    float wx0 = 1.0f - wx1, wy0 = 1.0f - wy1, wz0 = 1.0f - wz1;
    unsigned x0 = (unsigned)x0f, y0 = (unsigned)y0f, z0 = (unsigned)z0f;
    const unsigned P1 = 2654435761u, P2 = 805459861u;
    unsigned hy0 = y0 * P1, hy1 = (y0 + 1u) * P1;
    unsigned hz0 = z0 * P2, hz1 = (z0 + 1u) * P2;
    s[0] = hy0 ^ hz0;  wyz[0] = wy0 * wz0;
    s[1] = hy0 ^ hz1;  wyz[1] = wy0 * wz1;
    s[2] = hy1 ^ hz0;  wyz[2] = wy1 * wz0;
    s[3] = hy1 ^ hz1;  wyz[3] = wy1 * wz1;
    *x0out = x0; wx[0] = wx0; wx[1] = wx1;
}

// Legacy full-prep for fallback/tail paths.
__device__ __forceinline__ void hg_prep(
    float px, float py, float pz, float res,
    unsigned* __restrict__ idx, float* __restrict__ w)
{
    unsigned s[4]; float wyz[4], wx[2]; unsigned x0;
    hg_prep2(px, py, pz, res, s, wyz, &x0, wx);
    #pragma unroll
    for (int j = 0; j < 4; ++j) {
        idx[j]     = (x0 ^ s[j]) & HG_TABLE_MASK;        w[j]     = wx[0] * wyz[j];
        idx[4 + j] = ((x0 + 1u) ^ s[j]) & HG_TABLE_MASK; w[4 + j] = wx[1] * wyz[j];
    }
}

// ---------- Phase 1: balanced XCD-phased gather -> ws [16][N] ----------
__global__ __launch_bounds__(256) void hashgrid_gather_lvl(
    const float* __restrict__ xyz,
    const float* __restrict__ tables,
    const int*   __restrict__ resolutions,
    float*       __restrict__ ws,       // [16][n] float2, as floats
    int n_points)
{
    const int x    = blockIdx.x & 7;    // XCD (blockIdx%8 round-robin)
    const int slot = blockIdx.x >> 3;   // position in XCD x's work queue
    const int C    = (n_points + 511) >> 9;  // 512-point chunks per level

    // Phase 1 (slot < C): level 8+x exclusively (one 4MB table per XCD L2).
    // Phase 2 (slot >= C): flat item list [L7|L6|...|L0] x C chunks,
    //   XCD x takes items g = (slot-C)*8 + x -> every XCD gets C/8 chunks
    //   of EVERY level: equal queue length, equal work mix, levels stay
    //   synchronized across XCDs (one table per L2 at a time).
    int level, chunk;
    if (slot < C) {
        level = 8 + x; chunk = slot;
    } else {
        int g = ((slot - C) << 3) + x;   // [0, 8C)
        int d = g / C;                   // 0..7
        level = 7 - d;
        chunk = g - d * C;
    }
    if (chunk >= C) return;

    const float res = (float)resolutions[level];
    const float2* __restrict__ tbl =
        (const float2*)tables + (size_t)level * HG_TABLE_SIZE;
    float* __restrict__ wlev = ws + (size_t)level * n_points * 2;

    const int p0 = (chunk << 9) + ((int)threadIdx.x << 1);   // 2 pts/thread
    if (p0 >= n_points) return;

    if (p0 + 1 < n_points) {
        const float* xp = xyz + (size_t)p0 * 3;
        vf2 c0 = *(const vf2*)(xp);
        vf2 c1 = *(const vf2*)(xp + 2);
        vf2 c2 = *(const vf2*)(xp + 4);

        unsigned sA[4], sB[4], x0A, x0B;
        float wyzA[4], wyzB[4], wxA[2], wxB[2];
        hg_prep2(c0.x, c0.y, c1.x, res, sA, wyzA, &x0A, wxA);
        hg_prep2(c1.y, c2.x, c2.y, res, sB, wyzB, &x0B, wxB);

        unsigned iA0[4], iA1[4], iB0[4], iB1[4];
        #pragma unroll
        for (int j = 0; j < 4; ++j) {
            iA0[j] = (x0A ^ sA[j]) & HG_TABLE_MASK;
            iA1[j] = ((x0A + 1u) ^ sA[j]) & HG_TABLE_MASK;
            iB0[j] = (x0B ^ sB[j]) & HG_TABLE_MASK;
            iB1[j] = ((x0B + 1u) ^ sB[j]) & HG_TABLE_MASK;
        }
        const bool oddA = (x0A & 1u) != 0u;
        const bool oddB = (x0B & 1u) != 0u;

        // 8 unconditional 16B paired loads (line containing corner x-offset 0;
        // for even x0 the same 16B also holds corner x-offset 1).
        vf4 qA[4], qB[4];
        #pragma unroll
        for (int j = 0; j < 4; ++j) qA[j] = *(const vf4*)(tbl + (iA0[j] & ~1u));
        #pragma unroll
        for (int j = 0; j < 4; ++j) qB[j] = *(const vf4*)(tbl + (iB0[j] & ~1u));

        // predicated 8B loads of the +x corner for odd-x0 lanes only
        vf2 eA[4], eB[4];
        #pragma unroll
        for (int j = 0; j < 4; ++j) { eA[j] = (vf2)(0.f); eB[j] = (vf2)(0.f); }
        if (oddA) {
            #pragma unroll
            for (int j = 0; j < 4; ++j) eA[j] = *(const vf2*)(tbl + iA1[j]);
        }
        if (oddB) {
            #pragma unroll
            for (int j = 0; j < 4; ++j) eB[j] = *(const vf2*)(tbl + iB1[j]);
        }

        // Pin everything simultaneously live -> loads can't sink, MLP stays up.
        asm volatile(""
            : "+v"(qA[0]), "+v"(qA[1]), "+v"(qA[2]), "+v"(qA[3]),
              "+v"(qB[0]), "+v"(qB[1]), "+v"(qB[2]), "+v"(qB[3]),
              "+v"(eA[0]), "+v"(eA[1]), "+v"(eA[2]), "+v"(eA[3]),
              "+v"(eB[0]), "+v"(eB[1]), "+v"(eB[2]), "+v"(eB[3])
            :
            : "memory");

        float oax = 0.f, oay = 0.f, obx = 0.f, oby = 0.f;
        #pragma unroll
        for (int j = 0; j < 4; ++j) {
            bool hi = (iA0[j] & 1u) != 0u;
            vf2 lo;  lo.x  = qA[j].x; lo.y  = qA[j].y;
            vf2 hiv; hiv.x = qA[j].z; hiv.y = qA[j].w;
            vf2 f0 = hi ? hiv : lo;                  // corner x-offset 0
            vf2 f1 = oddA ? eA[j] : (hi ? lo : hiv); // corner x-offset 1
            float w0 = wxA[0] * wyzA[j], w1 = wxA[1] * wyzA[j];
            oax += w0 * f0.x + w1 * f1.x;
            oay += w0 * f0.y + w1 * f1.y;
        }
        #pragma unroll
        for (int j = 0; j < 4; ++j) {
            bool hi = (iB0[j] & 1u) != 0u;
            vf2 lo;  lo.x  = qB[j].x; lo.y  = qB[j].y;
            vf2 hiv; hiv.x = qB[j].z; hiv.y = qB[j].w;
            vf2 f0 = hi ? hiv : lo;
            vf2 f1 = oddB ? eB[j] : (hi ? lo : hiv);
            float w0 = wxB[0] * wyzB[j], w1 = wxB[1] * wyzB[j];
            obx += w0 * f0.x + w1 * f1.x;
            oby += w0 * f0.y + w1 * f1.y;
        }

        vf4 v; v.x = oax; v.y = oay; v.z = obx; v.w = oby;
        __builtin_nontemporal_store(v, (vf4*)(wlev + 2 * (size_t)p0)); // 16B aligned
    } else {
        // tail: single point, unpaired path
        float px = xyz[(size_t)p0 * 3 + 0];
        float py = xyz[(size_t)p0 * 3 + 1];
        float pz = xyz[(size_t)p0 * 3 + 2];
        unsigned idx[8]; float w[8];
        hg_prep(px, py, pz, res, idx, w);
        vf2 f[8];
        #pragma unroll
        for (int k = 0; k < 8; ++k) f[k] = *(const vf2*)(tbl + idx[k]);
        float sx = 0.f, sy = 0.f;
        #pragma unroll
        for (int k = 0; k < 8; ++k) { sx += w[k] * f[k].x; sy += w[k] * f[k].y; }
        vf2 v; v.x = sx; v.y = sy;
        __builtin_nontemporal_store(v, (vf2*)(wlev + 2 * (size_t)p0));
    }
}

// ---------- Phase 2: transpose ws [16][N] -> out [N][16], float4 both sides ----------
#define TP_PTS 256
#define TP_STRIDE (2 * TP_PTS + 4)   // floats per LDS row (pad 4 -> <=2-way conflicts)

__global__ __launch_bounds__(256) void hashgrid_transpose(
    const float* __restrict__ ws,
    float*       __restrict__ out,
    int n_points)
{
    __shared__ float tile[16 * TP_STRIDE];   // ~33 KB, level-major
    const int p0 = blockIdx.x * TP_PTS;
    const int t  = (int)threadIdx.x;
    const int npts = min(TP_PTS, n_points - p0);

    #pragma unroll
    for (int it = 0; it < 8; ++it) {
        int r  = it * 2 + (t >> 7);
        int q  = t & 127;
        int pt = q * 2;
        if (pt < npts) {
            const float* src = ws + (size_t)r * n_points * 2 + (size_t)(p0 + pt) * 2;
            vf4 v;
            if (pt + 1 < npts) v = *(const vf4*)src;
            else { vf2 v2 = *(const vf2*)src; v.x = v2.x; v.y = v2.y; v.z = 0.f; v.w = 0.f; }
            *(vf4*)&tile[r * TP_STRIDE + 4 * q] = v;
        }
    }
    __syncthreads();

    #pragma unroll
    for (int it = 0; it < 8; ++it) {
        int linear = it * 256 + t;
        int pt = linear >> 3;
        int v4 = linear & 7;
        if (pt < npts) {
            vf4 v;
            #pragma unroll
            for (int k = 0; k < 4; ++k) {
                int e = 4 * v4 + k;
                int lev = e >> 1, f = e & 1;
                v[k] = tile[lev * TP_STRIDE + 2 * pt + f];
            }
            __builtin_nontemporal_store(
                v, (vf4*)(out + (size_t)(p0 + pt) * 32 + 4 * v4));
        }
    }
}

// ---------- Fallback: single-kernel version ----------
__global__ __launch_bounds__(256) void hashgrid_fwd(
    const float* __restrict__ xyz,
    const float* __restrict__ tables,
    const int*   __restrict__ resolutions,
    float*       __restrict__ out,
    int n_points)
{
    int tid   = blockIdx.x * blockDim.x + threadIdx.x;
    int point = tid >> 4;
    int level = tid & 15;
    if (point >= n_points) return;

    float px = xyz[point * 3 + 0];
    float py = xyz[point * 3 + 1];
    float pz = xyz[point * 3 + 2];
    float res = (float)resolutions[level];
    const float2* __restrict__ tbl =
        (const float2*)tables + (size_t)level * HG_TABLE_SIZE;

    unsigned idx[8]; float w[8];
    hg_prep(px, py, pz, res, idx, w);
    vf2 f[8];
    #pragma unroll
    for (int k = 0; k < 8; ++k) f[k] = *(const vf2*)(tbl + idx[k]);
    float ox = 0.f, oy = 0.f;
    #pragma unroll
    for (int k = 0; k < 8; ++k) { ox += w[k] * f[k].x; oy += w[k] * f[k].y; }
    vf2 v; v.x = ox; v.y = oy;
    *(vf2*)(out + (size_t)point * 32 + 2 * level) = v;
}

extern "C" void kernel_launch(void* const* d_in, const int* in_sizes, int n_in,
                              void* d_out, int out_size, void* d_ws, size_t ws_size,
                              hipStream_t stream) {
    const float* xyz         = (const float*)d_in[0];
    const float* tables      = (const float*)d_in[1];
    const int*   resolutions = (const int*)d_in[2];
    float*       out         = (float*)d_out;

    int n_points = in_sizes[0] / 3;
    size_t ws_needed = (size_t)n_points * HG_N_LEVELS * sizeof(float2);

    if (ws_size >= ws_needed) {
        float* ws = (float*)d_ws;
        int C = (n_points + 511) >> 9;
        int slots = 2 * C;               // phase 1 (C) + phase 2 (C)
        hashgrid_gather_lvl<<<8 * slots, 256, 0, stream>>>(
            xyz, tables, resolutions, ws, n_points);
        int tblocks = (n_points + TP_PTS - 1) / TP_PTS;
        hashgrid_transpose<<<tblocks, 256, 0, stream>>>(ws, out, n_points);
    } else {
        int n_threads = n_points * HG_N_LEVELS;
        hashgrid_fwd<<<(n_threads + 255) / 256, 256, 0, stream>>>(
            xyz, tables, resolutions, out, n_points);
    }
}